// Round 1
// baseline (228.300 us; speedup 1.0000x reference)
//
#include <hip/hip_runtime.h>

#define BATCH 4096
#define NTRI  128
#define DIM   64

struct Smem {
    float anchor[2][DIM];   // [0]=item_origin, [1]=user_0
    float acc[2][DIM];      // [0]=e_v, [1]=e_u
    float sim[NTRI];
    float part[4][DIM];     // per-wave partials
    int   idx[2 * NTRI];    // [0..127]=h indices, [128..255]=t indices
};

__device__ __forceinline__ float4 xorsum4(float4 a, int m) {
    a.x += __shfl_xor(a.x, m, 64);
    a.y += __shfl_xor(a.y, m, 64);
    a.z += __shfl_xor(a.z, m, 64);
    a.w += __shfl_xor(a.w, m, 64);
    return a;
}

// mean over the 128 staged h-embeddings -> anchor[1] and acc[1]
__device__ __forceinline__ void gather_mean(const float* __restrict__ ent,
                                            Smem& sm, int tid) {
    const int lane = tid & 63, wv = tid >> 6;
    const int sub = lane >> 4, ql = lane & 15, dbase = ql * 4;
    float4 acc = make_float4(0.f, 0.f, 0.f, 0.f);
#pragma unroll
    for (int i = 0; i < 8; ++i) {
        const int t = wv * 32 + i * 4 + sub;
        const size_t idx = (size_t)sm.idx[t];
        const float4 tv = *(const float4*)(ent + idx * DIM + dbase);
        acc.x += tv.x; acc.y += tv.y; acc.z += tv.z; acc.w += tv.w;
    }
    acc = xorsum4(acc, 16);
    acc = xorsum4(acc, 32);
    if (sub == 0) *(float4*)(&sm.part[wv][dbase]) = acc;
    __syncthreads();
    if (tid < 16) {
        const float4 p0 = *(const float4*)(&sm.part[0][tid * 4]);
        const float4 p1 = *(const float4*)(&sm.part[1][tid * 4]);
        const float4 p2 = *(const float4*)(&sm.part[2][tid * 4]);
        const float4 p3 = *(const float4*)(&sm.part[3][tid * 4]);
        float4 r;
        const float inv = 1.0f / 128.0f;
        r.x = ((p0.x + p1.x) + (p2.x + p3.x)) * inv;
        r.y = ((p0.y + p1.y) + (p2.y + p3.y)) * inv;
        r.z = ((p0.z + p1.z) + (p2.z + p3.z)) * inv;
        r.w = ((p0.w + p1.w) + (p2.w + p3.w)) * inv;
        *(float4*)(&sm.anchor[1][tid * 4]) = r;
        *(float4*)(&sm.acc[1][tid * 4]) = r;
    }
    __syncthreads();
}

// one attention layer using staged sm.idx (h,t); accumulates into acc[side]
__device__ __forceinline__ void attention(const float* __restrict__ ent,
                                          Smem& sm, int side, int tid) {
    const int lane = tid & 63, wv = tid >> 6;
    const int sub = lane >> 4, ql = lane & 15, dbase = ql * 4;
    const float4 anc = *(const float4*)(&sm.anchor[side][dbase]);

    // 1) sims: each 16-lane quarter owns one triple per iter
#pragma unroll
    for (int i = 0; i < 8; ++i) {
        const int t = wv * 32 + i * 4 + sub;
        const size_t idx = (size_t)sm.idx[t];
        const float4 h = *(const float4*)(ent + idx * DIM + dbase);
        float v = h.x * anc.x + h.y * anc.y + h.z * anc.z + h.w * anc.w;
        v += __shfl_xor(v, 1, 64);
        v += __shfl_xor(v, 2, 64);
        v += __shfl_xor(v, 4, 64);
        v += __shfl_xor(v, 8, 64);
        if (ql == 0) sm.sim[t] = v;
    }
    __syncthreads();

    // 2) softmax over 128 sims, wave 0 only
    if (wv == 0) {
        float v0 = sm.sim[lane], v1 = sm.sim[lane + 64];
        float m = fmaxf(v0, v1);
#pragma unroll
        for (int off = 32; off; off >>= 1) m = fmaxf(m, __shfl_xor(m, off, 64));
        const float e0 = __expf(v0 - m), e1 = __expf(v1 - m);
        float s = e0 + e1;
#pragma unroll
        for (int off = 32; off; off >>= 1) s += __shfl_xor(s, off, 64);
        const float inv = 1.0f / s;
        sm.sim[lane]      = e0 * inv;
        sm.sim[lane + 64] = e1 * inv;
    }
    __syncthreads();

    // 3) weighted sum of tail embeddings
    float4 acc = make_float4(0.f, 0.f, 0.f, 0.f);
#pragma unroll
    for (int i = 0; i < 8; ++i) {
        const int t = wv * 32 + i * 4 + sub;
        const size_t idx = (size_t)sm.idx[NTRI + t];
        const float4 tv = *(const float4*)(ent + idx * DIM + dbase);
        const float w = sm.sim[t];
        acc.x += w * tv.x; acc.y += w * tv.y;
        acc.z += w * tv.z; acc.w += w * tv.w;
    }
    acc = xorsum4(acc, 16);
    acc = xorsum4(acc, 32);
    if (sub == 0) *(float4*)(&sm.part[wv][dbase]) = acc;
    __syncthreads();
    if (tid < 16) {
        const float4 p0 = *(const float4*)(&sm.part[0][tid * 4]);
        const float4 p1 = *(const float4*)(&sm.part[1][tid * 4]);
        const float4 p2 = *(const float4*)(&sm.part[2][tid * 4]);
        const float4 p3 = *(const float4*)(&sm.part[3][tid * 4]);
        float4* a = (float4*)(&sm.acc[side][tid * 4]);
        float4 cur = *a;
        cur.x += (p0.x + p1.x) + (p2.x + p3.x);
        cur.y += (p0.y + p1.y) + (p2.y + p3.y);
        cur.z += (p0.z + p1.z) + (p2.z + p3.z);
        cur.w += (p0.w + p1.w) + (p2.w + p3.w);
        *a = cur;
    }
    __syncthreads();
}

__global__ __launch_bounds__(256) void KCDN_67997922230517_kernel(
    const int* __restrict__ items,
    const int* __restrict__ user_h, const int* __restrict__ user_t,
    const int* __restrict__ item_h, const int* __restrict__ item_t,
    const float* __restrict__ ent, float* __restrict__ out) {
    __shared__ __align__(16) Smem sm;
    const int b = blockIdx.x;
    const int tid = threadIdx.x;

    // stage user layer-0 indices + item anchor
    {
        const size_t off0 = (size_t)b * NTRI;   // layer 0
        if (tid < NTRI) sm.idx[tid] = user_h[off0 + tid];
        else            sm.idx[tid] = user_t[off0 + (tid - NTRI)];
        if (tid < 16) {
            const size_t ii = (size_t)items[b] * DIM + tid * 4;
            const float4 v = *(const float4*)(ent + ii);
            *(float4*)(&sm.anchor[0][tid * 4]) = v;
            *(float4*)(&sm.acc[0][tid * 4])    = v;
        }
    }
    __syncthreads();

    gather_mean(ent, sm, tid);      // user_0 anchor from staged h
    attention(ent, sm, 1, tid);     // user layer 0 (idx still staged)

    // user layer 1
    {
        const size_t off1 = ((size_t)BATCH + b) * NTRI;
        if (tid < NTRI) sm.idx[tid] = user_h[off1 + tid];
        else            sm.idx[tid] = user_t[off1 + (tid - NTRI)];
    }
    __syncthreads();
    attention(ent, sm, 1, tid);

    // item layer 0
    {
        const size_t off0 = (size_t)b * NTRI;
        if (tid < NTRI) sm.idx[tid] = item_h[off0 + tid];
        else            sm.idx[tid] = item_t[off0 + (tid - NTRI)];
    }
    __syncthreads();
    attention(ent, sm, 0, tid);

    // item layer 1
    {
        const size_t off1 = ((size_t)BATCH + b) * NTRI;
        if (tid < NTRI) sm.idx[tid] = item_h[off1 + tid];
        else            sm.idx[tid] = item_t[off1 + (tid - NTRI)];
    }
    __syncthreads();
    attention(ent, sm, 0, tid);

    // final: sigmoid(e_v . e_u)
    if (tid < 64) {
        float v = sm.acc[0][tid] * sm.acc[1][tid];
#pragma unroll
        for (int off = 32; off; off >>= 1) v += __shfl_xor(v, off, 64);
        if (tid == 0) out[b] = 1.0f / (1.0f + __expf(-v));
    }
}

extern "C" void kernel_launch(void* const* d_in, const int* in_sizes, int n_in,
                              void* d_out, int out_size, void* d_ws, size_t ws_size,
                              hipStream_t stream) {
    // d_in order: items, user_h, user_r, user_t, item_h, item_r, item_t,
    //             entity_emb, relation_emb  (r / relation_emb unused by reference)
    const int*   items  = (const int*)d_in[0];
    const int*   user_h = (const int*)d_in[1];
    const int*   user_t = (const int*)d_in[3];
    const int*   item_h = (const int*)d_in[4];
    const int*   item_t = (const int*)d_in[6];
    const float* ent    = (const float*)d_in[7];
    float*       out    = (float*)d_out;

    hipLaunchKernelGGL(KCDN_67997922230517_kernel, dim3(BATCH), dim3(256), 0, stream,
                       items, user_h, user_t, item_h, item_t, ent, out);
}